// Round 8
// baseline (350.353 us; speedup 1.0000x reference)
//
#include <hip/hip_runtime.h>
#include <hip/hip_bf16.h>

// Problem constants
#define BATCH 16
#define CH    512
#define NPIX  1024
#define GRP   32
#define CPG   16

typedef __attribute__((ext_vector_type(8))) short bf16x8;
typedef __attribute__((ext_vector_type(4))) float f32x4;

__device__ __forceinline__ ushort f2b(float f) {
    union { float f; unsigned u; } v; v.f = f;
    unsigned u = v.u;
    u += 0x7FFF + ((u >> 16) & 1);   // round-to-nearest-even
    return (ushort)(u >> 16);
}

// async global->LDS, 16B per lane. LDS dest must be wave-uniform base + lane*16.
#define GLD16(gp, lp) __builtin_amdgcn_global_load_lds( \
    (__attribute__((address_space(1))) void*)(gp), \
    (__attribute__((address_space(3))) void*)(lp), 16, 0, 0)

#define MFMA(a, b, c) __builtin_amdgcn_mfma_f32_16x16x32_bf16(a, b, c, 0, 0, 0)

// ---------------- weight conversion f32 -> bf16 ----------------
__global__ __launch_bounds__(256) void convert_weights(
    const float* __restrict__ wq, const float* __restrict__ wp,
    ushort* __restrict__ wq_b, ushort* __restrict__ wp_b) {
    int i = blockIdx.x * 256 + threadIdx.x;   // 1048576 total
    if (i < 786432) wq_b[i] = f2b(wq[i]);
    else            wp_b[i - 786432] = f2b(wp[i - 786432]);
}

// ---------------- GroupNorm stats ----------------
__global__ __launch_bounds__(256) void gn_stats(
    const float* __restrict__ x, float* __restrict__ mu, float* __restrict__ rs) {
    int g = blockIdx.x, b = blockIdx.y;
    const float4* p = (const float4*)(x + ((size_t)b * CH + g * CPG) * NPIX); // 16384 contiguous
    float s = 0.f, ss = 0.f;
    for (int i = threadIdx.x; i < 4096; i += 256) {
        float4 v = p[i];
        s  += v.x + v.y + v.z + v.w;
        ss += v.x*v.x + v.y*v.y + v.z*v.z + v.w*v.w;
    }
    for (int o = 1; o < 64; o <<= 1) { s += __shfl_xor(s, o); ss += __shfl_xor(ss, o); }
    __shared__ float as[4], bs[4];
    int w = threadIdx.x >> 6;
    if ((threadIdx.x & 63) == 0) { as[w] = s; bs[w] = ss; }
    __syncthreads();
    if (threadIdx.x == 0) {
        s  = as[0] + as[1] + as[2] + as[3];
        ss = bs[0] + bs[1] + bs[2] + bs[3];
        float m = s * (1.0f / 16384.0f);
        float var = ss * (1.0f / 16384.0f) - m * m;
        mu[b * GRP + g] = m;
        rs[b * GRP + g] = rsqrtf(var + 1e-5f);
    }
}

// ---------------- GroupNorm normalize + LDS-transposed coalesced write ----------------
__global__ __launch_bounds__(256) void gn_norm_t(
    const float* __restrict__ x, const float* __restrict__ mu, const float* __restrict__ rs,
    const float* __restrict__ gamma, const float* __restrict__ beta, ushort* __restrict__ hT) {
    int c0 = blockIdx.x * 32, n0 = blockIdx.y * 128, b = blockIdx.z;
    __shared__ ushort t[128 * 32];
    int tid = threadIdx.x;
#pragma unroll
    for (int i = 0; i < 4; i++) {
        int f = tid + i * 256;          // 1024 float4 chunks: c in [0,32), nf in [0,32)
        int c = f >> 5, nf = f & 31;
        int cg = c0 + c;
        float m = mu[b * GRP + (cg >> 4)], r = rs[b * GRP + (cg >> 4)];
        float ga = gamma[cg] * r;
        float be = beta[cg] - m * ga;
        float4 v = *(const float4*)(x + ((size_t)(b * CH + cg)) * NPIX + n0 + nf * 4);
        float vv[4] = {v.x, v.y, v.z, v.w};
#pragma unroll
        for (int j = 0; j < 4; j++) {
            int n = nf * 4 + j;
            int pos = (c >> 3) ^ ((n >> 2) & 3);
            t[n * 32 + pos * 8 + (c & 7)] = f2b(vv[j] * ga + be);
        }
    }
    __syncthreads();
#pragma unroll
    for (int i = 0; i < 2; i++) {
        int ch = tid + i * 256;         // 512 chunks: n in [0,128), g in [0,4)
        int n = ch >> 2, g = ch & 3;
        int pos = g ^ ((n >> 2) & 3);
        uint4 val = *(const uint4*)&t[n * 32 + pos * 8];
        *(uint4*)(hT + ((size_t)b * NPIX + n0 + n) * CH + c0 + g * 8) = val;
    }
}

// ---------------- fused attention: S = qk^T, u = exp(S*scale), O1T = (u·v^T)/rowsum ------
// Per block: batch b, 32 q-rows. O[32x512] f32 resident in 64 acc VGPRs/lane.
// Max-free softmax -> purely linear accumulation, no online rescale.
// q tile LDS-resident (32 KB, XOR-swizzled). Per j-chunk (64 cols, 16 chunks):
//   S-phase: k B-frags REGISTER-DIRECT from global (16 rows x 64B fully-consumed
//            lines, L2-hot), fully unrolled 16-step MFMA<->load interleave, no barrier.
//   exp -> P chunk (4 KB LDS round trip, C-layout -> A-layout)
//   PV-phase: vb B-frags register-direct; waves split c into 4 slices of 128.
// XCD swizzle pins each batch's k+vb (~4 MB) into one XCD's L2.
#define QT 32
#define JT 64

__global__ __launch_bounds__(256, 2) void attn_fused(
    const ushort* __restrict__ qk, const ushort* __restrict__ vb,
    ushort* __restrict__ O1T, float scale) {
    __shared__ __align__(16) ushort qs[QT * 512];   // 32 KB
    __shared__ __align__(16) ushort ps[QT * JT];    // 4 KB
    __shared__ float rsbuf[2][QT];
    int flat = blockIdx.x;
    int xcd = flat & 7, idx = flat >> 3;
    int b = xcd * 2 + (idx & 1);            // 2 batches per XCD
    int m0 = (idx >> 1) * QT;
    const ushort* qkb = qk + (size_t)b * (NPIX * 1024);
    const ushort* vbb = vb + (size_t)b * (CH * NPIX);
    int tid = threadIdx.x, lane = tid & 63, wave = tid >> 6;
    int q = lane >> 4, l = lane & 15;
    int wm = (wave >> 1) * 16, wn = (wave & 1) * 32;   // S-phase wave tile 16x32
    int cslice = wave * 128;                            // PV-phase c-slice

    // stage q tile (rows m0..m0+31, cols 0..511), swizzle pos = (G&~7)|((G&7)^(r&7))
#pragma unroll
    for (int i = 0; i < 8; i++) {
        int s = tid + i * 256, r = s >> 6, pos = s & 63;
        int G = (pos & ~7) | ((pos & 7) ^ (r & 7));
        GLD16(qkb + (size_t)(m0 + r) * 1024 + G * 8, qs + s * 8);
    }

    // k-invariant LDS lane addresses
    const ushort* qbe = qs + (wm + l) * 512 + ((q ^ (l & 7)) * 8);          // even t
    const ushort* qbo = qs + (wm + l) * 512 + (((q | 4) ^ (l & 7)) * 8);    // odd t
    const ushort* pb00 = ps + l * 64 + ((q ^ (l & 7)) * 8);                 // mi=0 kk=0
    const ushort* pb01 = ps + l * 64 + (((4 + q) ^ (l & 7)) * 8);           // mi=0 kk=1
    const ushort* pb10 = pb00 + 16 * 64;                                    // mi=1 kk=0
    const ushort* pb11 = pb01 + 16 * 64;                                    // mi=1 kk=1
    // vb base pointers per ni (c rows cslice+ni*16+l)
    const ushort* pv[8];
#pragma unroll
    for (int ni = 0; ni < 8; ni++)
        pv[ni] = vbb + (size_t)(cslice + ni * 16 + l) * 1024 + q * 8;

    float rs[4] = {0.f, 0.f, 0.f, 0.f};
    f32x4 zero = {0.f, 0.f, 0.f, 0.f};
    f32x4 oacc[2][8];
#pragma unroll
    for (int mi = 0; mi < 2; mi++)
#pragma unroll
        for (int ni = 0; ni < 8; ni++) oacc[mi][ni] = zero;

    __syncthreads();   // q staging complete

    for (int jc = 0; jc < 16; jc++) {
        int j0 = jc * 64;
        // ---- S-phase: S[32x64] chunk, wave tile 16x32, K=512 ----
        f32x4 sacc0 = zero, sacc1 = zero;
        const ushort* pk0 = qkb + (size_t)(j0 + wn + l) * 1024 + 512 + q * 8;
        const ushort* pk1 = pk0 + 16 * 1024;
#pragma unroll
        for (int t = 0; t < 16; t++) {
            bf16x8 a = *(const bf16x8*)(((t & 1) ? qbo : qbe) + (t >> 1) * 64);
            bf16x8 b0 = *(const bf16x8*)(pk0 + t * 32);
            bf16x8 b1 = *(const bf16x8*)(pk1 + t * 32);
            sacc0 = MFMA(a, b0, sacc0);
            sacc1 = MFMA(a, b1, sacc1);
        }
        // ---- exp, P write (A-layout swizzled), rowsum partials ----
#pragma unroll
        for (int rg = 0; rg < 4; rg++) {
            int row = wm + q * 4 + rg;
            float u0 = __expf(sacc0[rg] * scale);
            float u1 = __expf(sacc1[rg] * scale);
            rs[rg] += u0 + u1;
            int c0i = wn + l, c1i = wn + 16 + l;
            ps[row * 64 + (((c0i >> 3) ^ (row & 7)) * 8) + (c0i & 7)] = f2b(u0);
            ps[row * 64 + (((c1i >> 3) ^ (row & 7)) * 8) + (c1i & 7)] = f2b(u1);
        }
        __syncthreads();
        // ---- PV-phase: O[32 x cslice+128] += P[32x64] * vb^T ----
#pragma unroll
        for (int kk = 0; kk < 2; kk++) {
            bf16x8 pa0 = *(const bf16x8*)((kk ? pb01 : pb00));
            bf16x8 pa1 = *(const bf16x8*)((kk ? pb11 : pb10));
#pragma unroll
            for (int ni = 0; ni < 8; ni++) {
                bf16x8 vv = *(const bf16x8*)(pv[ni] + j0 + kk * 32);
                oacc[0][ni] = MFMA(pa0, vv, oacc[0][ni]);
                oacc[1][ni] = MFMA(pa1, vv, oacc[1][ni]);
            }
        }
        __syncthreads();   // P buffer reusable next chunk
    }

    // ---- rowsum reduce (across l within q-group, then across wn-halves via LDS) ----
#pragma unroll
    for (int rg = 0; rg < 4; rg++) {
        float s = rs[rg];
        s += __shfl_xor(s, 1); s += __shfl_xor(s, 2);
        s += __shfl_xor(s, 4); s += __shfl_xor(s, 8);
        if (l == 0) rsbuf[wave & 1][wm + q * 4 + rg] = s;
    }
    __syncthreads();

    // ---- divide + store O1T[b][i][c] bf16 ----
#pragma unroll
    for (int mi = 0; mi < 2; mi++) {
        float inv[4];
#pragma unroll
        for (int rg = 0; rg < 4; rg++) {
            int r = mi * 16 + q * 4 + rg;
            inv[rg] = 1.0f / (rsbuf[0][r] + rsbuf[1][r]);
        }
#pragma unroll
        for (int ni = 0; ni < 8; ni++) {
            int c = cslice + ni * 16 + l;
#pragma unroll
            for (int rg = 0; rg < 4; rg++) {
                int i = m0 + mi * 16 + q * 4 + rg;
                O1T[((size_t)b * NPIX + i) * CH + c] = f2b(oacc[mi][ni][rg] * inv[rg]);
            }
        }
    }
}

// ---------------- generic bf16 gemm_bt<EPI,BM,BN>: C[m][n] = sum_k A[m][k]*Bt[n][k] --------
// R4 structure: single-buffered BK=64, global_load_lds width=16, XOR-swizzled LDS.
// EPI 0: qkv. n0<1024: direct q/k store. n0>=1024: LDS transpose -> coalesced v[c][j].
// EPI 3: out (f32, + bias[m] + resid)
#define BK 64

template<int EPI, int BMt, int BNt>
__global__ __launch_bounds__(256, 4) void gemm_bt(
    const ushort* __restrict__ A, long sA, int lda,
    const ushort* __restrict__ Bt, long sB, int ldb,
    int K,
    void* __restrict__ Out, long sO, int ldo,
    const float* __restrict__ bias,
    const float* __restrict__ resid,
    ushort* __restrict__ vout,
    float scale) {
    constexpr int FM = BMt / 32;
    constexpr int FN = BNt / 32;
    constexpr int SA = BMt / 32;
    constexpr int SB = BNt / 32;
    __shared__ __align__(16) ushort sh[(BMt + BNt) * BK];
    ushort* As = sh;
    ushort* Bs = sh + BMt * BK;
    int b = blockIdx.z;
    A  += (size_t)b * sA;
    Bt += (size_t)b * sB;
    int m0 = blockIdx.y * BMt, n0 = blockIdx.x * BNt;
    int tid = threadIdx.x;
    int lane = tid & 63;
    int wave = tid >> 6;
    int q = lane >> 4, l = lane & 15;
    int wm = (wave >> 1) * (BMt / 2), wn = (wave & 1) * (BNt / 2);

    int aoff[SA], boff[SB], lofa[SA], lofb[SB];
#pragma unroll
    for (int i = 0; i < SA; i++) {
        int p = tid + i * 256, r = p >> 3, g = (p & 7) ^ (r & 7);
        aoff[i] = (m0 + r) * lda + g * 8;
        lofa[i] = p * 8;
    }
#pragma unroll
    for (int i = 0; i < SB; i++) {
        int p = tid + i * 256, r = p >> 3, g = (p & 7) ^ (r & 7);
        boff[i] = (n0 + r) * ldb + g * 8;
        lofb[i] = p * 8;
    }

    int offA[FM][2], offB[FN][2];
#pragma unroll
    for (int mi = 0; mi < FM; mi++) {
        int r = wm + mi * 16 + l;
#pragma unroll
        for (int kk = 0; kk < 2; kk++)
            offA[mi][kk] = r * 64 + ((((kk << 2) | q) ^ (r & 7)) * 8);
    }
#pragma unroll
    for (int ni = 0; ni < FN; ni++) {
        int r = wn + ni * 16 + l;
#pragma unroll
        for (int kk = 0; kk < 2; kk++)
            offB[ni][kk] = r * 64 + ((((kk << 2) | q) ^ (r & 7)) * 8);
    }

    f32x4 zero = {0.f, 0.f, 0.f, 0.f};
    f32x4 acc[FM][FN];
#pragma unroll
    for (int mi = 0; mi < FM; mi++)
#pragma unroll
        for (int ni = 0; ni < FN; ni++) acc[mi][ni] = zero;

    for (int k0 = 0; k0 < K; k0 += BK) {
        __syncthreads();
#pragma unroll
        for (int i = 0; i < SA; i++) GLD16(A + aoff[i] + k0, As + lofa[i]);
#pragma unroll
        for (int i = 0; i < SB; i++) GLD16(Bt + boff[i] + k0, Bs + lofb[i]);
        __syncthreads();
#pragma unroll
        for (int kk = 0; kk < 2; kk++) {
            bf16x8 af[FM], bfr[FN];
#pragma unroll
            for (int mi = 0; mi < FM; mi++) af[mi]  = *(const bf16x8*)(As + offA[mi][kk]);
#pragma unroll
            for (int ni = 0; ni < FN; ni++) bfr[ni] = *(const bf16x8*)(Bs + offB[ni][kk]);
#pragma unroll
            for (int mi = 0; mi < FM; mi++)
#pragma unroll
                for (int ni = 0; ni < FN; ni++)
                    acc[mi][ni] = MFMA(af[mi], bfr[ni], acc[mi][ni]);
        }
    }

    // epilogue; C/D frag: row m = q*4+reg, col n = l (m89-verified mapping)
    if (EPI == 0) {
        if (n0 >= 1024) {
            __syncthreads();
#pragma unroll
            for (int mi = 0; mi < FM; mi++)
#pragma unroll
                for (int ni = 0; ni < FN; ni++) {
                    int nl = wn + ni * 16 + l;
                    float bi = bias[n0 + nl];
#pragma unroll
                    for (int rg = 0; rg < 4; rg++) {
                        int ml = wm + mi * 16 + q * 4 + rg;
                        int pos = (ml >> 3) ^ (nl & 15);
                        sh[nl * 128 + pos * 8 + (ml & 7)] = f2b(acc[mi][ni][rg] + bi);
                    }
                }
            __syncthreads();
#pragma unroll
            for (int i = 0; i < 8; i++) {
                int idx = tid + i * 256;
                int nl = idx >> 4, ch = idx & 15;
                int g2 = ch ^ (nl & 15);
                uint4 val = *(const uint4*)&sh[nl * 128 + g2 * 8];
                *(uint4*)(vout + (size_t)b * (512 * 1024)
                          + (size_t)(n0 - 1024 + nl) * 1024 + m0 + ch * 8) = val;
            }
            return;
        }
#pragma unroll
        for (int mi = 0; mi < FM; mi++)
#pragma unroll
            for (int ni = 0; ni < FN; ni++) {
                int n = n0 + wn + ni * 16 + l;
                float bi = bias[n];
#pragma unroll
                for (int rg = 0; rg < 4; rg++) {
                    int m = m0 + wm + mi * 16 + q * 4 + rg;
                    ((ushort*)Out)[(size_t)b * sO + (size_t)m * ldo + n] =
                        f2b(acc[mi][ni][rg] + bi);
                }
            }
        return;
    }
    // EPI == 3
#pragma unroll
    for (int mi = 0; mi < FM; mi++)
#pragma unroll
        for (int ni = 0; ni < FN; ni++) {
            int mbase = m0 + wm + mi * 16 + q * 4;
            int n = n0 + wn + ni * 16 + l;
#pragma unroll
            for (int rg = 0; rg < 4; rg++) {
                int m = mbase + rg;
                float v = acc[mi][ni][rg] + bias[m] + resid[(size_t)b * sO + (size_t)m * ldo + n];
                ((float*)Out)[(size_t)b * sO + (size_t)m * ldo + n] = v;
            }
        }
}

extern "C" void kernel_launch(void* const* d_in, const int* in_sizes, int n_in,
                              void* d_out, int out_size, void* d_ws, size_t ws_size,
                              hipStream_t stream) {
    const float* x     = (const float*)d_in[0];
    const float* gamma = (const float*)d_in[1];
    const float* beta  = (const float*)d_in[2];
    const float* wqkv  = (const float*)d_in[3];
    const float* bqkv  = (const float*)d_in[4];
    const float* wproj = (const float*)d_in[5];
    const float* bproj = (const float*)d_in[6];
    float* out = (float*)d_out;
    char* ws = (char*)d_ws;

    // workspace layout (bytes); total ~69 MB
    ushort* wq_b   = (ushort*)(ws + 0);          // 1.5 MB
    ushort* wp_b   = (ushort*)(ws + 1572864);    // 0.5 MB
    float*  mu     = (float*)(ws + 2097152);     // 2 KB
    float*  rs     = (float*)(ws + 2099200);     // 2 KB
    ushort* hT     = (ushort*)(ws + 2101248);    // 16 MB [b][n][c]  (reused as O1T)
    ushort* qk     = (ushort*)(ws + 18878464);   // 32 MB [b][n][q0..511,k512..1023]
    ushort* vb     = (ushort*)(ws + 52432896);   // 16 MB [b][c][j]
    ushort* O1T    = hT;                          // alias: hT dead after MM1

    convert_weights<<<4096, 256, 0, stream>>>(wqkv, wproj, wq_b, wp_b);
    gn_stats<<<dim3(GRP, BATCH), 256, 0, stream>>>(x, mu, rs);
    gn_norm_t<<<dim3(16, 8, BATCH), 256, 0, stream>>>(x, mu, rs, gamma, beta, hT);

    // MM1: qkvT[n][o] = sum_c hT[n][c] * Wqkv[o][c]  (M=1024, N=1536, K=512)
    gemm_bt<0, 128, 128><<<dim3(12, 8, BATCH), 256, 0, stream>>>(
        hT, 524288, 512, wq_b, 0, 512, 512,
        qk, 1048576, 1024, bqkv, nullptr, vb, 0.f);

    // Fused attention: replaces MM2 + softmax + MM3 (no u materialization)
    attn_fused<<<512, 256, 0, stream>>>(qk, vb, O1T, 0.044194173824159216f);

    // MM4: out[o][n] = sum_c Wp[o][c] * O1T[n][c] + bproj[o] + x  (M=512, N=1024, K=512)
    gemm_bt<3, 64, 128><<<dim3(8, 8, BATCH), 256, 0, stream>>>(
        wp_b, 0, 512, O1T, 524288, 512, 512,
        out, 524288, 1024, bproj, x, nullptr, 0.f);
}